// Round 14
// baseline (2288.708 us; speedup 1.0000x reference)
//
#include <hip/hip_runtime.h>
#include <hip/hip_bf16.h>
#include <math.h>

#define TT 1024
#define BB 2
#define DD 768
#define HH 12
#define NHD 64
#define LL 12
#define VV 50257
#define MROWS (BB*TT)
#define VPAD 50304   // 393*128
#define NT 393       // logits n-tiles
#define NROWS (MROWS*HH)   // 24576 (b,t,h) attention rows

typedef __attribute__((ext_vector_type(4))) float f32x4;
typedef __attribute__((ext_vector_type(8))) __bf16 bf16x8;
typedef __attribute__((ext_vector_type(8))) unsigned short u16x8;
typedef __hip_bfloat16 bf16;

__device__ __forceinline__ void gload_lds16(const bf16* g, bf16* l) {
    __builtin_amdgcn_global_load_lds((const __attribute__((address_space(1))) void*)g,
                                     (__attribute__((address_space(3))) void*)l, 16, 0, 0);
}

// ---------------- embedding ----------------
__global__ void embed_kernel(const int* __restrict__ idx, const float* __restrict__ wte,
                             const float* __restrict__ wpe, float* __restrict__ x) {
    int m = blockIdx.x;
    int t = m % TT;
    int tok = idx[m];
    const float* wrow = wte + (size_t)tok * DD;
    const float* prow = wpe + (size_t)t * DD;
    float* xrow = x + (size_t)m * DD;
    for (int c = threadIdx.x; c < DD; c += blockDim.x)
        xrow[c] = wrow[c] + prow[c];
}

// ---------------- layernorm: fp32 in -> bf16 out (layer-0 only) ----------------
__global__ void ln_kernel(const float* __restrict__ x, const float* __restrict__ w,
                          const float* __restrict__ b, bf16* __restrict__ out) {
    __shared__ float red[256];
    int m = blockIdx.x;
    int tid = threadIdx.x;
    const float* xr = x + (size_t)m * DD;
    float v0 = xr[tid], v1 = xr[tid + 256], v2 = xr[tid + 512];
    red[tid] = v0 + v1 + v2;
    __syncthreads();
    for (int s = 128; s > 0; s >>= 1) { if (tid < s) red[tid] += red[tid + s]; __syncthreads(); }
    float mu = red[0] * (1.0f / DD);
    __syncthreads();
    float d0 = v0 - mu, d1 = v1 - mu, d2 = v2 - mu;
    red[tid] = d0 * d0 + d1 * d1 + d2 * d2;
    __syncthreads();
    for (int s = 128; s > 0; s >>= 1) { if (tid < s) red[tid] += red[tid + s]; __syncthreads(); }
    float rstd = rsqrtf(red[0] * (1.0f / DD) + 1e-5f);
    bf16* orow = out + (size_t)m * DD;
    orow[tid]       = __float2bfloat16(d0 * rstd * w[tid]       + b[tid]);
    orow[tid + 256] = __float2bfloat16(d1 * rstd * w[tid + 256] + b[tid + 256]);
    orow[tid + 512] = __float2bfloat16(d2 * rstd * w[tid + 512] + b[tid + 512]);
}

// ---------------- fused split-K reduce + residual + LayerNorm ----------------
__global__ void redln_kernel(const float* __restrict__ part, const float* __restrict__ bias,
                             const float* __restrict__ w, const float* __restrict__ b,
                             float* __restrict__ x, bf16* __restrict__ hb) {
    __shared__ float red[256];
    const size_t MN = (size_t)MROWS * DD;
    int m = blockIdx.x;
    int tid = threadIdx.x;
    float v[3];
    #pragma unroll
    for (int j = 0; j < 3; ++j) {
        int c = tid + j * 256;
        size_t i = (size_t)m * DD + c;
        v[j] = x[i] + part[i] + part[MN + i] + bias[c];
        x[i] = v[j];
    }
    red[tid] = v[0] + v[1] + v[2];
    __syncthreads();
    for (int s = 128; s > 0; s >>= 1) { if (tid < s) red[tid] += red[tid + s]; __syncthreads(); }
    float mu = red[0] * (1.0f / DD);
    __syncthreads();
    float d0 = v[0] - mu, d1 = v[1] - mu, d2 = v[2] - mu;
    red[tid] = d0 * d0 + d1 * d1 + d2 * d2;
    __syncthreads();
    for (int s = 128; s > 0; s >>= 1) { if (tid < s) red[tid] += red[tid + s]; __syncthreads(); }
    float rstd = rsqrtf(red[0] * (1.0f / DD) + 1e-5f);
    bf16* orow = hb + (size_t)m * DD;
    orow[tid]       = __float2bfloat16(d0 * rstd * w[tid]       + b[tid]);
    orow[tid + 256] = __float2bfloat16(d1 * rstd * w[tid + 256] + b[tid + 256]);
    orow[tid + 512] = __float2bfloat16(d2 * rstd * w[tid + 512] + b[tid + 512]);
}

// ---------------- fp32 -> bf16 cast (wte) ----------------
__global__ void cast_kernel(const float* __restrict__ src, bf16* __restrict__ dst, int n4) {
    int stride = gridDim.x * blockDim.x;
    for (int i = blockIdx.x * blockDim.x + threadIdx.x; i < n4; i += stride) {
        float4 v = *(const float4*)(src + (size_t)i * 4);
        bf16* d = dst + (size_t)i * 4;
        d[0] = __float2bfloat16(v.x); d[1] = __float2bfloat16(v.y);
        d[2] = __float2bfloat16(v.z); d[3] = __float2bfloat16(v.w);
    }
}

__global__ void padzero_kernel(bf16* __restrict__ p, int n) {
    int i = blockIdx.x * 256 + threadIdx.x;
    if (i < n) p[i] = __float2bfloat16(0.f);
}

// ---------------- batched W[K,N] fp32 -> Wt[N,K] bf16 ----------------
__global__ void tcast_kernel(const float* __restrict__ W, bf16* __restrict__ Wt,
                             int K, int N, size_t wstride, size_t tstride) {
    W  += (size_t)blockIdx.z * wstride;
    Wt += (size_t)blockIdx.z * tstride;
    __shared__ float t[32][33];
    int n0 = blockIdx.x * 32, k0 = blockIdx.y * 32;
    int c = threadIdx.x & 31, g = threadIdx.x >> 5;
    #pragma unroll
    for (int i = 0; i < 4; ++i) {
        int k = g * 4 + i;
        t[k][c] = W[(size_t)(k0 + k) * N + n0 + c];
    }
    __syncthreads();
    #pragma unroll
    for (int i = 0; i < 4; ++i) {
        int n = g * 4 + i;
        Wt[(size_t)(n0 + n) * K + k0 + c] = __float2bfloat16(t[c][n]);
    }
}

// ---------------- MFMA GEMM, BK=64: C[M,N] = A[M,K] @ Wt[N,K]^T --------------
template<int BM, int BN, bool BIAS, bool GELU_, bool RES, bool OUTBF16, bool SPLITK>
__global__ __launch_bounds__(256, 3) void mgemm(
        const bf16* __restrict__ A, const bf16* __restrict__ Bm,
        const float* __restrict__ bias, const float* __restrict__ res,
        float* __restrict__ Cf, bf16* __restrict__ Cb, int M, int N, int K) {
    constexpr int WM = BM / 32, WN = BN / 32;
    constexpr int RA = BM / 32, RB = BN / 32;
    constexpr int NL = RA + RB;
    __shared__ __align__(16) bf16 As[2][BM * 64];
    __shared__ __align__(16) bf16 Bs[2][BN * 64];
    const int tid = threadIdx.x, lane = tid & 63, wid = tid >> 6;
    const int nbx = gridDim.x;
    const int nwg = nbx * gridDim.y;
    const int bidl = blockIdx.x + nbx * blockIdx.y;
    const int cpx = nwg >> 3;
    const int sw = (bidl & 7) * cpx + (bidl >> 3);
    const int m0 = (sw % nbx) * BM, n0 = (sw / nbx) * BN;
    const int wr = (wid >> 1) * (BM / 2), wc = (wid & 1) * (BN / 2);
    const int fr = lane & 15, fq = lane >> 4;

    const int Keff  = SPLITK ? (K >> 1) : K;
    const int kbase = SPLITK ? blockIdx.z * Keff : 0;
    if (SPLITK) Cf += (size_t)blockIdx.z * M * N;

    const int srow = tid >> 3;
    const int sk   = ((tid & 7) ^ (srow & 7)) * 8;
    const bf16* gA = A  + (size_t)(m0 + srow) * K + kbase + sk;
    const bf16* gB = Bm + (size_t)(n0 + srow) * K + kbase + sk;

    const int nt = Keff / 64;
    f32x4 acc[WM][WN] = {};

    auto stage = [&](int t) {
        bf16* dA = &As[t & 1][0] + tid * 8;
        bf16* dB = &Bs[t & 1][0] + tid * 8;
        const bf16* pA = gA + t * 64;
        const bf16* pB = gB + t * 64;
        #pragma unroll
        for (int u = 0; u < RA; ++u) gload_lds16(pA + (size_t)(u * 32) * K, dA + u * 2048);
        #pragma unroll
        for (int u = 0; u < RB; ++u) gload_lds16(pB + (size_t)(u * 32) * K, dB + u * 2048);
    };

    stage(0);

    for (int t = 0; t < nt; ++t) {
        if (t + 1 < nt) {
            stage(t + 1);
            asm volatile("s_waitcnt vmcnt(%0)" :: "i"(NL) : "memory");
        } else {
            asm volatile("s_waitcnt vmcnt(0)" ::: "memory");
        }
        __builtin_amdgcn_s_barrier();
        __builtin_amdgcn_sched_barrier(0);
        const bf16* abase = &As[t & 1][0];
        const bf16* bbase = &Bs[t & 1][0];
        #pragma unroll
        for (int ks = 0; ks < 2; ++ks) {
            const int kp = ((ks * 4 + fq) ^ (fr & 7)) * 8;
            bf16x8 af[WM], bq[WN];
            #pragma unroll
            for (int m = 0; m < WM; ++m)
                af[m] = *(const bf16x8*)(abase + (wr + m * 16 + fr) * 64 + kp);
            #pragma unroll
            for (int n = 0; n < WN; ++n)
                bq[n] = *(const bf16x8*)(bbase + (wc + n * 16 + fr) * 64 + kp);
            #pragma unroll
            for (int m = 0; m < WM; ++m)
                #pragma unroll
                for (int n = 0; n < WN; ++n)
                    acc[m][n] = __builtin_amdgcn_mfma_f32_16x16x32_bf16(af[m], bq[n], acc[m][n], 0, 0, 0);
        }
        __builtin_amdgcn_sched_barrier(0);
        __builtin_amdgcn_s_barrier();
    }

    #pragma unroll
    for (int m = 0; m < WM; ++m) {
        const int row = m0 + wr + m * 16 + fq * 4;
        #pragma unroll
        for (int n = 0; n < WN; ++n) {
            const int col = n0 + wc + n * 16 + fr;
            float bv = BIAS ? bias[col] : 0.f;
            #pragma unroll
            for (int r = 0; r < 4; ++r) {
                float v = acc[m][n][r] + bv;
                if (GELU_) {
                    float u = v;
                    float z = 1.5957691216057308f * (u + 0.044715f * u * u * u);
                    v = u / (1.0f + __expf(-z));
                }
                if (RES) v += res[(size_t)(row + r) * N + col];
                if (OUTBF16) Cb[(size_t)(row + r) * N + col] = __float2bfloat16(v);
                else         Cf[(size_t)(row + r) * N + col] = v;
            }
        }
    }
}

// ---------------- proj GEMM with FUSED attn-combine A-staging ----------------
// A[row][k=h*64+d] = (po0*e0 + po1*e1)/l computed in-register -> swizzled LDS.
// B via gload_lds16. split-K=2 (z = blockIdx.z). C = part[z] (raw, no bias).
__global__ __launch_bounds__(256, 3) void mgemmP(
        const float* __restrict__ po, const float2* __restrict__ pml,
        const bf16* __restrict__ Bm, float* __restrict__ Cf) {
    constexpr int BM = 64, BN = 64;
    constexpr int M = MROWS, N = DD, K = DD;
    __shared__ __align__(16) bf16 As[2][BM * 64];
    __shared__ __align__(16) bf16 Bs[2][BN * 64];
    const int tid = threadIdx.x, lane = tid & 63, wid = tid >> 6;
    const int nbx = gridDim.x;
    const int nwg = nbx * gridDim.y;
    const int bidl = blockIdx.x + nbx * blockIdx.y;
    const int cpx = nwg >> 3;
    const int sw = (bidl & 7) * cpx + (bidl >> 3);
    const int m0 = (sw % nbx) * BM, n0 = (sw / nbx) * BN;
    const int wr = (wid >> 1) * 32, wc = (wid & 1) * 32;
    const int fr = lane & 15, fq = lane >> 4;

    const int Keff = K >> 1;                 // 384
    const int kbase = blockIdx.z * Keff;
    Cf += (size_t)blockIdx.z * (size_t)M * N;

    const int srow = tid >> 3;               // 0..31
    const int sk   = ((tid & 7) ^ (srow & 7)) * 8;   // source k within tile (0..56)
    const bf16* gB = Bm + (size_t)(n0 + srow) * K + kbase + sk;
    const size_t ZO = (size_t)MROWS * DD;
    const int h0 = kbase >> 6;               // head base for this split

    const int nt = Keff / 64;                // 6
    f32x4 acc[2][2] = {};

    auto stageB = [&](int t) {
        bf16* dB = &Bs[t & 1][0] + tid * 8;
        const bf16* pB = gB + t * 64;
        #pragma unroll
        for (int u = 0; u < 2; ++u) gload_lds16(pB + (size_t)(u * 32) * K, dB + u * 2048);
    };
    auto stageA = [&](int t) {
        bf16* dA = &As[t & 1][0] + tid * 8;
        const int h = h0 + t;
        #pragma unroll
        for (int u = 0; u < 2; ++u) {
            const int row = m0 + srow + u * 32;
            const size_t pidx = (size_t)row * HH + h;
            f32x4 a0 = *(const f32x4*)(po + pidx * NHD + sk);
            f32x4 a1 = *(const f32x4*)(po + pidx * NHD + sk + 4);
            f32x4 b0 = *(const f32x4*)(po + ZO + pidx * NHD + sk);
            f32x4 b1 = *(const f32x4*)(po + ZO + pidx * NHD + sk + 4);
            float2 ml0 = pml[pidx];
            float2 ml1 = pml[NROWS + pidx];
            float mt = fmaxf(ml0.x, ml1.x);
            float e0 = __expf(ml0.x - mt), e1 = __expf(ml1.x - mt);
            float inv = 1.f / (ml0.y * e0 + ml1.y * e1);
            e0 *= inv; e1 *= inv;
            union { bf16x8 v; bf16 h8[8]; } o;
            #pragma unroll
            for (int j = 0; j < 4; ++j) {
                o.h8[j]     = __float2bfloat16(a0[j] * e0 + b0[j] * e1);
                o.h8[j + 4] = __float2bfloat16(a1[j] * e0 + b1[j] * e1);
            }
            *(bf16x8*)(dA + u * 2048) = o.v;
        }
    };

    stageB(0); stageA(0);

    for (int t = 0; t < nt; ++t) {
        if (t + 1 < nt) {
            stageB(t + 1);           // async gloads fly under the combine VALU
            stageA(t + 1);
            asm volatile("s_waitcnt vmcnt(2)" ::: "memory");   // tile-t B landed
        } else {
            asm volatile("s_waitcnt vmcnt(0)" ::: "memory");
        }
        asm volatile("s_waitcnt lgkmcnt(0)" ::: "memory");     // own A ds_writes done
        __builtin_amdgcn_s_barrier();
        __builtin_amdgcn_sched_barrier(0);
        const bf16* abase = &As[t & 1][0];
        const bf16* bbase = &Bs[t & 1][0];
        #pragma unroll
        for (int ks = 0; ks < 2; ++ks) {
            const int kp = ((ks * 4 + fq) ^ (fr & 7)) * 8;
            bf16x8 af[2], bq[2];
            #pragma unroll
            for (int m = 0; m < 2; ++m)
                af[m] = *(const bf16x8*)(abase + (wr + m * 16 + fr) * 64 + kp);
            #pragma unroll
            for (int n = 0; n < 2; ++n)
                bq[n] = *(const bf16x8*)(bbase + (wc + n * 16 + fr) * 64 + kp);
            #pragma unroll
            for (int m = 0; m < 2; ++m)
                #pragma unroll
                for (int n = 0; n < 2; ++n)
                    acc[m][n] = __builtin_amdgcn_mfma_f32_16x16x32_bf16(af[m], bq[n], acc[m][n], 0, 0, 0);
        }
        __builtin_amdgcn_sched_barrier(0);
        __builtin_amdgcn_s_barrier();
    }

    #pragma unroll
    for (int m = 0; m < 2; ++m) {
        const int row = m0 + wr + m * 16 + fq * 4;
        #pragma unroll
        for (int n = 0; n < 2; ++n) {
            const int col = n0 + wc + n * 16 + fr;
            #pragma unroll
            for (int r = 0; r < 4; ++r)
                Cf[(size_t)(row + r) * N + col] = acc[m][n][r];
        }
    }
}

// ---------------- logits GEMM 256x128, 512 thr, BK=32 + fused loss partials --
__global__ __launch_bounds__(512, 4) void mgemmL(
        const bf16* __restrict__ A, const bf16* __restrict__ Bm,
        float* __restrict__ Cf, float2* __restrict__ P, int N, int K) {
    constexpr int NL = 3;
    __shared__ __align__(16) bf16 As[2][256 * 32];
    __shared__ __align__(16) bf16 Bs[2][128 * 32];
    __shared__ float2 lbuf[8][64];
    const int tid = threadIdx.x, lane = tid & 63, wid = tid >> 6;
    const int nbx = gridDim.x;
    const int nwg = nbx * gridDim.y;
    const int bidl = blockIdx.x + nbx * blockIdx.y;
    const int cpx = nwg >> 3;
    const int sw = (bidl & 7) * cpx + (bidl >> 3);
    const int m0 = (sw % nbx) * 256, n0 = (sw / nbx) * 128;
    const int wm = wid >> 1, wn = wid & 1;
    const int wr = wm * 64, wc = wn * 64;
    const int fr = lane & 15, fq = lane >> 4;

    const int srow = tid >> 2;
    const int ksrc = ((tid & 3) ^ ((tid >> 3) & 3)) * 8;
    const bf16* gA = A  + (size_t)(m0 + srow) * K + ksrc;
    const bf16* gB = Bm + (size_t)(n0 + srow) * K + ksrc;
    const int kph = (fq ^ ((fr >> 1) & 3)) * 8;

    f32x4 acc[4][4] = {};
    const int nt = K / 32;

    auto stage = [&](int t) {
        bf16* dA = &As[t & 1][0] + tid * 8;
        bf16* dB = &Bs[t & 1][0] + tid * 8;
        const bf16* pA = gA + t * 32;
        #pragma unroll
        for (int u = 0; u < 2; ++u) gload_lds16(pA + (size_t)(u * 128) * K, dA + u * 4096);
        gload_lds16(gB + t * 32, dB);
    };

    stage(0);

    for (int t = 0; t < nt; ++t) {
        if (t + 1 < nt) {
            stage(t + 1);
            asm volatile("s_waitcnt vmcnt(%0)" :: "i"(NL) : "memory");
        } else {
            asm volatile("s_waitcnt vmcnt(0)" ::: "memory");
        }
        __builtin_amdgcn_s_barrier();
        __builtin_amdgcn_sched_barrier(0);
        const bf16* abase = &As[t & 1][0];
        const bf16* bbase = &Bs[t & 1][0];
        bf16x8 af[4], bq[4];
        #pragma unroll
        for (int m = 0; m < 4; ++m)
            af[m] = *(const bf16x8*)(abase + (wr + m * 16 + fr) * 32 + kph);
        #pragma unroll
        for (int n = 0; n < 4; ++n)
            bq[n] = *(const bf16x8*)(bbase + (wc + n * 16 + fr) * 32 + kph);
        #pragma unroll
        for (int m = 0; m < 4; ++m)
            #pragma unroll
            for (int n = 0; n < 4; ++n)
                acc[m][n] = __builtin_amdgcn_mfma_f32_16x16x32_bf16(af[m], bq[n], acc[m][n], 0, 0, 0);
        __builtin_amdgcn_sched_barrier(0);
        __builtin_amdgcn_s_barrier();
    }

    #pragma unroll
    for (int m = 0; m < 4; ++m) {
        const int row = m0 + wr + m * 16 + fq * 4;
        #pragma unroll
        for (int n = 0; n < 4; ++n) {
            const int col = n0 + wc + n * 16 + fr;
            if (col < N) {
                #pragma unroll
                for (int r = 0; r < 4; ++r)
                    Cf[(size_t)(row + r) * N + col] = acc[m][n][r];
            }
        }
    }
    #pragma unroll
    for (int m = 0; m < 4; ++m) {
        #pragma unroll
        for (int r = 0; r < 4; ++r) {
            float mx = -1e30f;
            #pragma unroll
            for (int n = 0; n < 4; ++n) {
                int col = n0 + wc + n * 16 + fr;
                mx = fmaxf(mx, (col < N) ? acc[m][n][r] : -1e30f);
            }
            #pragma unroll
            for (int msk = 1; msk <= 8; msk <<= 1) mx = fmaxf(mx, __shfl_xor(mx, msk));
            float sm = 0.f;
            #pragma unroll
            for (int n = 0; n < 4; ++n) {
                int col = n0 + wc + n * 16 + fr;
                if (col < N) sm += __expf(acc[m][n][r] - mx);
            }
            #pragma unroll
            for (int msk = 1; msk <= 8; msk <<= 1) sm += __shfl_xor(sm, msk);
            if (fr == 0) lbuf[wid][m * 16 + fq * 4 + r] = make_float2(mx, sm);
        }
    }
    __syncthreads();
    if (tid < 256) {
        int band = tid >> 6, rl = tid & 63;
        float2 a = lbuf[band * 2][rl];
        float2 b = lbuf[band * 2 + 1][rl];
        float mc = fmaxf(a.x, b.x);
        float sc = a.y * __expf(a.x - mc) + b.y * __expf(b.x - mc);
        P[(size_t)(m0 + band * 64 + rl) * NT + (n0 >> 7)] = make_float2(mc, sc);
    }
}

// ---------------- MFMA flash attention, KV-split-2 ----------------
__global__ __launch_bounds__(256) void attn3_kernel(const bf16* __restrict__ qkv,
                                                    float* __restrict__ po,
                                                    float2* __restrict__ pml) {
    __shared__ bf16 Vt[64 * 64];
    __shared__ bf16 Ps[4][16 * 64];
    const int bid = blockIdx.x;
    const int z = blockIdx.y;
    const int q0 = (15 - (bid & 15)) * 64;
    const int h  = (bid / (TT / 64)) % HH;
    const int b  = bid / ((TT / 64) * HH);
    const int tid = threadIdx.x, lane = tid & 63, wid = tid >> 6;
    const int fr = lane & 15, fq = lane >> 4;
    const size_t rs = 3 * DD;

    const int nt_all = q0 / 64 + 1;
    const int lo = z ? (nt_all + 1) / 2 : 0;
    const int hi = z ? nt_all : (nt_all + 1) / 2;

    po  += (size_t)z * MROWS * DD;
    pml += (size_t)z * NROWS;

    if (lo >= hi) {
        #pragma unroll
        for (int r = 0; r < 4; ++r) {
            int q = q0 + wid * 16 + fq * 4 + r;
            size_t pidx = ((size_t)(b * TT + q) * HH + h);
            #pragma unroll
            for (int n2 = 0; n2 < 4; ++n2)
                po[pidx * NHD + n2 * 16 + fr] = 0.f;
            if (fr == 0) pml[pidx] = make_float2(-1e30f, 0.f);
        }
        return;
    }

    bf16x8 qf[2];
    {
        const bf16* qb = qkv + (size_t)(b * TT + q0 + wid * 16 + fr) * rs + h * NHD;
        qf[0] = *(const bf16x8*)(qb + fq * 8);
        qf[1] = *(const bf16x8*)(qb + 32 + fq * 8);
    }
    float mrun[4] = {-1e30f, -1e30f, -1e30f, -1e30f};
    float lrun[4] = {0.f, 0.f, 0.f, 0.f};
    f32x4 o[4] = {};
    const int vrow = (tid & 31) * 2, kq = tid >> 5;

    for (int jt = lo; jt < hi; ++jt) {
        __syncthreads();
        {
            const u16x8* vb = (const u16x8*)(qkv + (size_t)(b * TT + jt * 64 + vrow) * rs + 2 * DD + h * NHD + kq * 8);
            u16x8 v0 = vb[0];
            u16x8 v1 = *(const u16x8*)((const bf16*)vb + rs);
            #pragma unroll
            for (int j = 0; j < 8; ++j) {
                int d = kq * 8 + j;
                int e = (d * 64 + vrow) ^ ((d & 7) << 3);
                *(unsigned int*)&Vt[e] = (unsigned int)v0[j] | ((unsigned int)v1[j] << 16);
            }
        }
        f32x4 s[4] = {};
        const bf16* kb = qkv + (size_t)(b * TT + jt * 64 + fr) * rs + DD + h * NHD;
        __builtin_amdgcn_s_setprio(1);
        #pragma unroll
        for (int n = 0; n < 4; ++n) {
            bf16x8 k0 = *(const bf16x8*)(kb + (size_t)(n * 16) * rs + fq * 8);
            bf16x8 k1 = *(const bf16x8*)(kb + (size_t)(n * 16) * rs + 32 + fq * 8);
            s[n] = __builtin_amdgcn_mfma_f32_16x16x32_bf16(qf[0], k0, s[n], 0, 0, 0);
            s[n] = __builtin_amdgcn_mfma_f32_16x16x32_bf16(qf[1], k1, s[n], 0, 0, 0);
        }
        __builtin_amdgcn_s_setprio(0);
        float mt[4] = {-1e30f, -1e30f, -1e30f, -1e30f};
        #pragma unroll
        for (int n = 0; n < 4; ++n) {
            int colg = jt * 64 + n * 16 + fr;
            #pragma unroll
            for (int r = 0; r < 4; ++r) {
                int rowg = q0 + wid * 16 + fq * 4 + r;
                float v = s[n][r] * 0.125f;
                if (colg > rowg) v = -1e30f;
                s[n][r] = v;
                mt[r] = fmaxf(mt[r], v);
            }
        }
        #pragma unroll
        for (int msk = 1; msk <= 8; msk <<= 1)
            #pragma unroll
            for (int r = 0; r < 4; ++r) mt[r] = fmaxf(mt[r], __shfl_xor(mt[r], msk));
        float sc[4], pt[4] = {0.f, 0.f, 0.f, 0.f};
        #pragma unroll
        for (int r = 0; r < 4; ++r) {
            float mn = fmaxf(mrun[r], mt[r]);
            sc[r] = __expf(mrun[r] - mn);
            mrun[r] = mn;
        }
        #pragma unroll
        for (int n = 0; n < 4; ++n)
            #pragma unroll
            for (int r = 0; r < 4; ++r) {
                float p = __expf(s[n][r] - mrun[r]);
                s[n][r] = p;
                pt[r] += p;
            }
        #pragma unroll
        for (int msk = 1; msk <= 8; msk <<= 1)
            #pragma unroll
            for (int r = 0; r < 4; ++r) pt[r] += __shfl_xor(pt[r], msk);
        #pragma unroll
        for (int r = 0; r < 4; ++r) lrun[r] = lrun[r] * sc[r] + pt[r];
        #pragma unroll
        for (int n2 = 0; n2 < 4; ++n2)
            #pragma unroll
            for (int r = 0; r < 4; ++r) o[n2][r] *= sc[r];
        #pragma unroll
        for (int n = 0; n < 4; ++n)
            #pragma unroll
            for (int r = 0; r < 4; ++r) {
                int row = fq * 4 + r;
                int e = (row * 64 + n * 16 + fr) ^ ((row & 7) << 3);
                Ps[wid][e] = __float2bfloat16(s[n][r]);
            }
        __syncthreads();
        __builtin_amdgcn_s_setprio(1);
        #pragma unroll
        for (int ks = 0; ks < 2; ++ks) {
            int pe = (fr * 64 + ks * 32 + fq * 8) ^ ((fr & 7) << 3);
            bf16x8 pa = *(const bf16x8*)&Ps[wid][pe];
            #pragma unroll
            for (int n2 = 0; n2 < 4; ++n2) {
                int d = n2 * 16 + fr;
                int ve = (d * 64 + ks * 32 + fq * 8) ^ ((d & 7) << 3);
                bf16x8 vv = *(const bf16x8*)&Vt[ve];
                o[n2] = __builtin_amdgcn_mfma_f32_16x16x32_bf16(pa, vv, o[n2], 0, 0, 0);
            }
        }
        __builtin_amdgcn_s_setprio(0);
    }
    #pragma unroll
    for (int r = 0; r < 4; ++r) {
        int q = q0 + wid * 16 + fq * 4 + r;
        size_t pidx = ((size_t)(b * TT + q) * HH + h);
        #pragma unroll
        for (int n2 = 0; n2 < 4; ++n2)
            po[pidx * NHD + n2 * 16 + fr] = o[n2][r];
        if (fr == 0) pml[pidx] = make_float2(mrun[r], lrun[r]);
    }
}

// ---------------- loss finish ----------------
__global__ void zero_kernel(float* p) { if (threadIdx.x == 0) p[0] = 0.f; }

__global__ void loss_finish(const float2* __restrict__ P, const float* __restrict__ logits,
                            const int* __restrict__ targets, float* __restrict__ acc) {
    __shared__ float rm[256], rs[256];
    int m = blockIdx.x;
    int tid = threadIdx.x;
    float mx = -1e30f, sm = 0.f;
    for (int i = tid; i < NT; i += 256) {
        float2 p = P[(size_t)m * NT + i];
        float nm = fmaxf(mx, p.x);
        sm = sm * __expf(mx - nm) + p.y * __expf(p.x - nm);
        mx = nm;
    }
    rm[tid] = mx; rs[tid] = sm;
    __syncthreads();
    for (int s = 128; s > 0; s >>= 1) {
        if (tid < s) {
            float m2 = rm[tid + s], s2 = rs[tid + s];
            float nm = fmaxf(rm[tid], m2);
            rs[tid] = rs[tid] * __expf(rm[tid] - nm) + s2 * __expf(m2 - nm);
            rm[tid] = nm;
        }
        __syncthreads();
    }
    if (tid == 0) {
        float lse = logf(rs[0]) + rm[0];
        atomicAdd(acc, lse - logits[(size_t)m * VV + targets[m]]);
    }
}

__global__ void loss_final(const float* __restrict__ acc, float* __restrict__ out) {
    if (threadIdx.x == 0) out[0] = acc[0] * (1.0f / (float)MROWS);
}

// ---------------- launch ----------------
extern "C" void kernel_launch(void* const* d_in, const int* in_sizes, int n_in,
                              void* d_out, int out_size, void* d_ws, size_t ws_size,
                              hipStream_t stream) {
    const int*   idx     = (const int*)d_in[0];
    const int*   targets = (const int*)d_in[1];
    const float* wte     = (const float*)d_in[2];
    const float* wpe     = (const float*)d_in[3];
    const float* ln1_w   = (const float*)d_in[4];
    const float* ln1_b   = (const float*)d_in[5];
    const float* qkv_w   = (const float*)d_in[6];
    const float* qkv_b   = (const float*)d_in[7];
    const float* proj_w  = (const float*)d_in[8];
    const float* proj_b  = (const float*)d_in[9];
    const float* ln2_w   = (const float*)d_in[10];
    const float* ln2_b   = (const float*)d_in[11];
    const float* fc_w    = (const float*)d_in[12];
    const float* fc_b    = (const float*)d_in[13];
    const float* fc2_w   = (const float*)d_in[14];
    const float* fc2_b   = (const float*)d_in[15];
    const float* lnf_w   = (const float*)d_in[16];
    const float* lnf_b   = (const float*)d_in[17];

    float* logits = (float*)d_out;
    float* loss_out = logits + (size_t)MROWS * VV;

    const size_t LQ = (size_t)3 * DD * DD, LP = (size_t)DD * DD;
    const size_t LF = (size_t)4 * DD * DD, LF2 = (size_t)4 * DD * DD;
    const size_t LSTRIDE = LQ + LP + LF + LF2;

    float* x    = (float*)d_ws;
    float* lacc = x + (size_t)MROWS * DD;
    float* part = lacc + 16;                                  // [2][MROWS*DD]; splitK out + loss P
    float* po   = part + (size_t)2 * MROWS * DD;              // [2][MROWS*DD] attn partial O
    float2* pml = (float2*)(po + (size_t)2 * MROWS * DD);     // [2][NROWS]
    bf16* qkvbuf = (bf16*)(pml + (size_t)2 * NROWS);
    bf16* hb   = qkvbuf + (size_t)MROWS * 3 * DD;
    bf16* gb   = hb + (size_t)MROWS * DD;
    bf16* wteb = gb + (size_t)MROWS * 4 * DD;
    bf16* wbase = wteb + (size_t)VPAD * DD;

    const size_t fixed_bytes = (size_t)((char*)wbase - (char*)d_ws);
    const bool hoist = ws_size >= fixed_bytes + sizeof(bf16) * LSTRIDE * LL;

    dim3 blk(256);
    cast_kernel<<<2048, blk, 0, stream>>>(wte, wteb, VV * DD / 4);
    padzero_kernel<<<((VPAD - VV) * DD + 255) / 256, blk, 0, stream>>>(
        wteb + (size_t)VV * DD, (VPAD - VV) * DD);
    embed_kernel<<<MROWS, blk, 0, stream>>>(idx, wte, wpe, x);

    if (hoist) {
        tcast_kernel<<<dim3(3 * DD / 32, DD / 32, LL), blk, 0, stream>>>(
            qkv_w, wbase, DD, 3 * DD, LQ, LSTRIDE);
        tcast_kernel<<<dim3(DD / 32, DD / 32, LL), blk, 0, stream>>>(
            proj_w, wbase + LQ, DD, DD, LP, LSTRIDE);
        tcast_kernel<<<dim3(4 * DD / 32, DD / 32, LL), blk, 0, stream>>>(
            fc_w, wbase + LQ + LP, DD, 4 * DD, LF, LSTRIDE);
        tcast_kernel<<<dim3(DD / 32, 4 * DD / 32, LL), blk, 0, stream>>>(
            fc2_w, wbase + LQ + LP + LF, 4 * DD, DD, LF2, LSTRIDE);
    }

    ln_kernel<<<MROWS, blk, 0, stream>>>(x, ln1_w, ln1_b, hb);

    for (int l = 0; l < LL; ++l) {
        bf16* wl = hoist ? wbase + (size_t)l * LSTRIDE : wbase;
        bf16* wQT = wl, *wPT = wl + LQ, *wFT = wl + LQ + LP, *wF2T = wl + LQ + LP + LF;
        if (!hoist) {
            tcast_kernel<<<dim3(3 * DD / 32, DD / 32, 1), blk, 0, stream>>>(qkv_w + (size_t)l * LQ, wQT, DD, 3 * DD, 0, 0);
            tcast_kernel<<<dim3(DD / 32, DD / 32, 1), blk, 0, stream>>>(proj_w + (size_t)l * LP, wPT, DD, DD, 0, 0);
            tcast_kernel<<<dim3(4 * DD / 32, DD / 32, 1), blk, 0, stream>>>(fc_w + (size_t)l * LF, wFT, DD, 4 * DD, 0, 0);
            tcast_kernel<<<dim3(DD / 32, 4 * DD / 32, 1), blk, 0, stream>>>(fc2_w + (size_t)l * LF2, wF2T, 4 * DD, DD, 0, 0);
        }

        mgemm<128, 64, true, false, false, true, false><<<dim3(MROWS / 128, 3 * DD / 64), blk, 0, stream>>>(
            hb, wQT, qkv_b + (size_t)l * 3 * DD, nullptr, nullptr, qkvbuf, MROWS, 3 * DD, DD);

        attn3_kernel<<<dim3(BB * HH * (TT / 64), 2), blk, 0, stream>>>(qkvbuf, po, pml);

        // proj with fused combine-in-A-staging; split-K=2 -> part
        mgemmP<<<dim3(MROWS / 64, DD / 64, 2), blk, 0, stream>>>(po, pml, wPT, part);
        redln_kernel<<<MROWS, blk, 0, stream>>>(part, proj_b + (size_t)l * DD,
            ln2_w + (size_t)l * DD, ln2_b + (size_t)l * DD, x, hb);

        mgemm<128, 64, true, true, false, true, false><<<dim3(MROWS / 128, 4 * DD / 64), blk, 0, stream>>>(
            hb, wFT, fc_b + (size_t)l * 4 * DD, nullptr, nullptr, gb, MROWS, 4 * DD, DD);

        mgemm<64, 64, false, false, false, false, true><<<dim3(MROWS / 64, DD / 64, 2), blk, 0, stream>>>(
            gb, wF2T, nullptr, nullptr, part, nullptr, MROWS, DD, 4 * DD);
        const float* nw = (l + 1 < LL) ? ln1_w + (size_t)(l + 1) * DD : lnf_w;
        const float* nb = (l + 1 < LL) ? ln1_b + (size_t)(l + 1) * DD : lnf_b;
        redln_kernel<<<MROWS, blk, 0, stream>>>(part, fc2_b + (size_t)l * DD, nw, nb, x, hb);
    }

    mgemmL<<<dim3(MROWS / 256, VPAD / 128), dim3(512), 0, stream>>>(
        hb, wteb, logits, (float2*)part, VV, DD);

    zero_kernel<<<1, 64, 0, stream>>>(lacc);
    loss_finish<<<MROWS, blk, 0, stream>>>((const float2*)part, logits, targets, lacc);
    loss_final<<<1, 64, 0, stream>>>(lacc, loss_out);
}

// Round 16
// 2182.078 us; speedup vs baseline: 1.0489x; 1.0489x over previous
//
#include <hip/hip_runtime.h>
#include <hip/hip_bf16.h>
#include <math.h>

#define TT 1024
#define BB 2
#define DD 768
#define HH 12
#define NHD 64
#define LL 12
#define VV 50257
#define MROWS (BB*TT)
#define VPAD 50304   // 393*128
#define NT 393       // logits n-tiles
#define NROWS (MROWS*HH)   // 24576 (b,t,h) attention rows

typedef __attribute__((ext_vector_type(4))) float f32x4;
typedef __attribute__((ext_vector_type(8))) __bf16 bf16x8;
typedef __attribute__((ext_vector_type(8))) unsigned short u16x8;
typedef __hip_bfloat16 bf16;

__device__ __forceinline__ void gload_lds16(const bf16* g, bf16* l) {
    __builtin_amdgcn_global_load_lds((const __attribute__((address_space(1))) void*)g,
                                     (__attribute__((address_space(3))) void*)l, 16, 0, 0);
}

// ---------------- embedding ----------------
__global__ void embed_kernel(const int* __restrict__ idx, const float* __restrict__ wte,
                             const float* __restrict__ wpe, float* __restrict__ x) {
    int m = blockIdx.x;
    int t = m % TT;
    int tok = idx[m];
    const float* wrow = wte + (size_t)tok * DD;
    const float* prow = wpe + (size_t)t * DD;
    float* xrow = x + (size_t)m * DD;
    for (int c = threadIdx.x; c < DD; c += blockDim.x)
        xrow[c] = wrow[c] + prow[c];
}

// ---------------- layernorm: fp32 in -> bf16 out (layer-0 only) ----------------
__global__ void ln_kernel(const float* __restrict__ x, const float* __restrict__ w,
                          const float* __restrict__ b, bf16* __restrict__ out) {
    __shared__ float red[256];
    int m = blockIdx.x;
    int tid = threadIdx.x;
    const float* xr = x + (size_t)m * DD;
    float v0 = xr[tid], v1 = xr[tid + 256], v2 = xr[tid + 512];
    red[tid] = v0 + v1 + v2;
    __syncthreads();
    for (int s = 128; s > 0; s >>= 1) { if (tid < s) red[tid] += red[tid + s]; __syncthreads(); }
    float mu = red[0] * (1.0f / DD);
    __syncthreads();
    float d0 = v0 - mu, d1 = v1 - mu, d2 = v2 - mu;
    red[tid] = d0 * d0 + d1 * d1 + d2 * d2;
    __syncthreads();
    for (int s = 128; s > 0; s >>= 1) { if (tid < s) red[tid] += red[tid + s]; __syncthreads(); }
    float rstd = rsqrtf(red[0] * (1.0f / DD) + 1e-5f);
    bf16* orow = out + (size_t)m * DD;
    orow[tid]       = __float2bfloat16(d0 * rstd * w[tid]       + b[tid]);
    orow[tid + 256] = __float2bfloat16(d1 * rstd * w[tid + 256] + b[tid + 256]);
    orow[tid + 512] = __float2bfloat16(d2 * rstd * w[tid + 512] + b[tid + 512]);
}

// ---------------- fused split-K reduce + residual + LayerNorm ----------------
__global__ void redln_kernel(const float* __restrict__ part, const float* __restrict__ bias,
                             const float* __restrict__ w, const float* __restrict__ b,
                             float* __restrict__ x, bf16* __restrict__ hb) {
    __shared__ float red[256];
    const size_t MN = (size_t)MROWS * DD;
    int m = blockIdx.x;
    int tid = threadIdx.x;
    float v[3];
    #pragma unroll
    for (int j = 0; j < 3; ++j) {
        int c = tid + j * 256;
        size_t i = (size_t)m * DD + c;
        v[j] = x[i] + part[i] + part[MN + i] + bias[c];
        x[i] = v[j];
    }
    red[tid] = v[0] + v[1] + v[2];
    __syncthreads();
    for (int s = 128; s > 0; s >>= 1) { if (tid < s) red[tid] += red[tid + s]; __syncthreads(); }
    float mu = red[0] * (1.0f / DD);
    __syncthreads();
    float d0 = v[0] - mu, d1 = v[1] - mu, d2 = v[2] - mu;
    red[tid] = d0 * d0 + d1 * d1 + d2 * d2;
    __syncthreads();
    for (int s = 128; s > 0; s >>= 1) { if (tid < s) red[tid] += red[tid + s]; __syncthreads(); }
    float rstd = rsqrtf(red[0] * (1.0f / DD) + 1e-5f);
    bf16* orow = hb + (size_t)m * DD;
    orow[tid]       = __float2bfloat16(d0 * rstd * w[tid]       + b[tid]);
    orow[tid + 256] = __float2bfloat16(d1 * rstd * w[tid + 256] + b[tid + 256]);
    orow[tid + 512] = __float2bfloat16(d2 * rstd * w[tid + 512] + b[tid + 512]);
}

// ---------------- fp32 -> bf16 cast (wte) ----------------
__global__ void cast_kernel(const float* __restrict__ src, bf16* __restrict__ dst, int n4) {
    int stride = gridDim.x * blockDim.x;
    for (int i = blockIdx.x * blockDim.x + threadIdx.x; i < n4; i += stride) {
        float4 v = *(const float4*)(src + (size_t)i * 4);
        bf16* d = dst + (size_t)i * 4;
        d[0] = __float2bfloat16(v.x); d[1] = __float2bfloat16(v.y);
        d[2] = __float2bfloat16(v.z); d[3] = __float2bfloat16(v.w);
    }
}

__global__ void padzero_kernel(bf16* __restrict__ p, int n) {
    int i = blockIdx.x * 256 + threadIdx.x;
    if (i < n) p[i] = __float2bfloat16(0.f);
}

// ---------------- batched W[K,N] fp32 -> Wt[N,K] bf16 ----------------
__global__ void tcast_kernel(const float* __restrict__ W, bf16* __restrict__ Wt,
                             int K, int N, size_t wstride, size_t tstride) {
    W  += (size_t)blockIdx.z * wstride;
    Wt += (size_t)blockIdx.z * tstride;
    __shared__ float t[32][33];
    int n0 = blockIdx.x * 32, k0 = blockIdx.y * 32;
    int c = threadIdx.x & 31, g = threadIdx.x >> 5;
    #pragma unroll
    for (int i = 0; i < 4; ++i) {
        int k = g * 4 + i;
        t[k][c] = W[(size_t)(k0 + k) * N + n0 + c];
    }
    __syncthreads();
    #pragma unroll
    for (int i = 0; i < 4; ++i) {
        int n = g * 4 + i;
        Wt[(size_t)(n0 + n) * K + k0 + c] = __float2bfloat16(t[c][n]);
    }
}

// ---------------- MFMA GEMM, BK=64: C[M,N] = A[M,K] @ Wt[N,K]^T --------------
template<int BM, int BN, bool BIAS, bool GELU_, bool RES, bool OUTBF16, bool SPLITK>
__global__ __launch_bounds__(256, 3) void mgemm(
        const bf16* __restrict__ A, const bf16* __restrict__ Bm,
        const float* __restrict__ bias, const float* __restrict__ res,
        float* __restrict__ Cf, bf16* __restrict__ Cb, int M, int N, int K) {
    constexpr int WM = BM / 32, WN = BN / 32;
    constexpr int RA = BM / 32, RB = BN / 32;
    constexpr int NL = RA + RB;
    __shared__ __align__(16) bf16 As[2][BM * 64];
    __shared__ __align__(16) bf16 Bs[2][BN * 64];
    const int tid = threadIdx.x, lane = tid & 63, wid = tid >> 6;
    const int nbx = gridDim.x;
    const int nwg = nbx * gridDim.y;
    const int bidl = blockIdx.x + nbx * blockIdx.y;
    const int cpx = nwg >> 3;
    const int sw = (bidl & 7) * cpx + (bidl >> 3);
    const int m0 = (sw % nbx) * BM, n0 = (sw / nbx) * BN;
    const int wr = (wid >> 1) * (BM / 2), wc = (wid & 1) * (BN / 2);
    const int fr = lane & 15, fq = lane >> 4;

    const int Keff  = SPLITK ? (K >> 1) : K;
    const int kbase = SPLITK ? blockIdx.z * Keff : 0;
    if (SPLITK) Cf += (size_t)blockIdx.z * M * N;

    const int srow = tid >> 3;
    const int sk   = ((tid & 7) ^ (srow & 7)) * 8;
    const bf16* gA = A  + (size_t)(m0 + srow) * K + kbase + sk;
    const bf16* gB = Bm + (size_t)(n0 + srow) * K + kbase + sk;

    const int nt = Keff / 64;
    f32x4 acc[WM][WN] = {};

    auto stage = [&](int t) {
        bf16* dA = &As[t & 1][0] + tid * 8;
        bf16* dB = &Bs[t & 1][0] + tid * 8;
        const bf16* pA = gA + t * 64;
        const bf16* pB = gB + t * 64;
        #pragma unroll
        for (int u = 0; u < RA; ++u) gload_lds16(pA + (size_t)(u * 32) * K, dA + u * 2048);
        #pragma unroll
        for (int u = 0; u < RB; ++u) gload_lds16(pB + (size_t)(u * 32) * K, dB + u * 2048);
    };

    stage(0);

    for (int t = 0; t < nt; ++t) {
        if (t + 1 < nt) {
            stage(t + 1);
            asm volatile("s_waitcnt vmcnt(%0)" :: "i"(NL) : "memory");
        } else {
            asm volatile("s_waitcnt vmcnt(0)" ::: "memory");
        }
        __builtin_amdgcn_s_barrier();
        __builtin_amdgcn_sched_barrier(0);
        const bf16* abase = &As[t & 1][0];
        const bf16* bbase = &Bs[t & 1][0];
        #pragma unroll
        for (int ks = 0; ks < 2; ++ks) {
            const int kp = ((ks * 4 + fq) ^ (fr & 7)) * 8;
            bf16x8 af[WM], bq[WN];
            #pragma unroll
            for (int m = 0; m < WM; ++m)
                af[m] = *(const bf16x8*)(abase + (wr + m * 16 + fr) * 64 + kp);
            #pragma unroll
            for (int n = 0; n < WN; ++n)
                bq[n] = *(const bf16x8*)(bbase + (wc + n * 16 + fr) * 64 + kp);
            #pragma unroll
            for (int m = 0; m < WM; ++m)
                #pragma unroll
                for (int n = 0; n < WN; ++n)
                    acc[m][n] = __builtin_amdgcn_mfma_f32_16x16x32_bf16(af[m], bq[n], acc[m][n], 0, 0, 0);
        }
        __builtin_amdgcn_sched_barrier(0);
        asm volatile("s_waitcnt lgkmcnt(0)" ::: "memory");   // all LDS reads retired
        __builtin_amdgcn_s_barrier();
    }

    #pragma unroll
    for (int m = 0; m < WM; ++m) {
        const int row = m0 + wr + m * 16 + fq * 4;
        #pragma unroll
        for (int n = 0; n < WN; ++n) {
            const int col = n0 + wc + n * 16 + fr;
            float bv = BIAS ? bias[col] : 0.f;
            #pragma unroll
            for (int r = 0; r < 4; ++r) {
                float v = acc[m][n][r] + bv;
                if (GELU_) {
                    float u = v;
                    float z = 1.5957691216057308f * (u + 0.044715f * u * u * u);
                    v = u / (1.0f + __expf(-z));
                }
                if (RES) v += res[(size_t)(row + r) * N + col];
                if (OUTBF16) Cb[(size_t)(row + r) * N + col] = __float2bfloat16(v);
                else         Cf[(size_t)(row + r) * N + col] = v;
            }
        }
    }
}

// ---------------- logits GEMM 256x128, 512 thr, BK=32 + fused loss partials --
__global__ __launch_bounds__(512, 4) void mgemmL(
        const bf16* __restrict__ A, const bf16* __restrict__ Bm,
        float* __restrict__ Cf, float2* __restrict__ P, int N, int K) {
    constexpr int NL = 3;
    __shared__ __align__(16) bf16 As[2][256 * 32];
    __shared__ __align__(16) bf16 Bs[2][128 * 32];
    __shared__ float2 lbuf[8][64];
    const int tid = threadIdx.x, lane = tid & 63, wid = tid >> 6;
    const int nbx = gridDim.x;
    const int nwg = nbx * gridDim.y;
    const int bidl = blockIdx.x + nbx * blockIdx.y;
    const int cpx = nwg >> 3;
    const int sw = (bidl & 7) * cpx + (bidl >> 3);
    const int m0 = (sw % nbx) * 256, n0 = (sw / nbx) * 128;
    const int wm = wid >> 1, wn = wid & 1;
    const int wr = wm * 64, wc = wn * 64;
    const int fr = lane & 15, fq = lane >> 4;

    const int srow = tid >> 2;
    const int ksrc = ((tid & 3) ^ ((tid >> 3) & 3)) * 8;
    const bf16* gA = A  + (size_t)(m0 + srow) * K + ksrc;
    const bf16* gB = Bm + (size_t)(n0 + srow) * K + ksrc;
    const int kph = (fq ^ ((fr >> 1) & 3)) * 8;

    f32x4 acc[4][4] = {};
    const int nt = K / 32;

    auto stage = [&](int t) {
        bf16* dA = &As[t & 1][0] + tid * 8;
        bf16* dB = &Bs[t & 1][0] + tid * 8;
        const bf16* pA = gA + t * 32;
        #pragma unroll
        for (int u = 0; u < 2; ++u) gload_lds16(pA + (size_t)(u * 128) * K, dA + u * 4096);
        gload_lds16(gB + t * 32, dB);
    };

    stage(0);

    for (int t = 0; t < nt; ++t) {
        if (t + 1 < nt) {
            stage(t + 1);
            asm volatile("s_waitcnt vmcnt(%0)" :: "i"(NL) : "memory");
        } else {
            asm volatile("s_waitcnt vmcnt(0)" ::: "memory");
        }
        __builtin_amdgcn_s_barrier();
        __builtin_amdgcn_sched_barrier(0);
        const bf16* abase = &As[t & 1][0];
        const bf16* bbase = &Bs[t & 1][0];
        bf16x8 af[4], bq[4];
        #pragma unroll
        for (int m = 0; m < 4; ++m)
            af[m] = *(const bf16x8*)(abase + (wr + m * 16 + fr) * 32 + kph);
        #pragma unroll
        for (int n = 0; n < 4; ++n)
            bq[n] = *(const bf16x8*)(bbase + (wc + n * 16 + fr) * 32 + kph);
        #pragma unroll
        for (int m = 0; m < 4; ++m)
            #pragma unroll
            for (int n = 0; n < 4; ++n)
                acc[m][n] = __builtin_amdgcn_mfma_f32_16x16x32_bf16(af[m], bq[n], acc[m][n], 0, 0, 0);
        __builtin_amdgcn_sched_barrier(0);
        asm volatile("s_waitcnt lgkmcnt(0)" ::: "memory");   // all LDS reads retired
        __builtin_amdgcn_s_barrier();
    }

    #pragma unroll
    for (int m = 0; m < 4; ++m) {
        const int row = m0 + wr + m * 16 + fq * 4;
        #pragma unroll
        for (int n = 0; n < 4; ++n) {
            const int col = n0 + wc + n * 16 + fr;
            if (col < N) {
                #pragma unroll
                for (int r = 0; r < 4; ++r)
                    Cf[(size_t)(row + r) * N + col] = acc[m][n][r];
            }
        }
    }
    #pragma unroll
    for (int m = 0; m < 4; ++m) {
        #pragma unroll
        for (int r = 0; r < 4; ++r) {
            float mx = -1e30f;
            #pragma unroll
            for (int n = 0; n < 4; ++n) {
                int col = n0 + wc + n * 16 + fr;
                mx = fmaxf(mx, (col < N) ? acc[m][n][r] : -1e30f);
            }
            #pragma unroll
            for (int msk = 1; msk <= 8; msk <<= 1) mx = fmaxf(mx, __shfl_xor(mx, msk));
            float sm = 0.f;
            #pragma unroll
            for (int n = 0; n < 4; ++n) {
                int col = n0 + wc + n * 16 + fr;
                if (col < N) sm += __expf(acc[m][n][r] - mx);
            }
            #pragma unroll
            for (int msk = 1; msk <= 8; msk <<= 1) sm += __shfl_xor(sm, msk);
            if (fr == 0) lbuf[wid][m * 16 + fq * 4 + r] = make_float2(mx, sm);
        }
    }
    __syncthreads();
    if (tid < 256) {
        int band = tid >> 6, rl = tid & 63;
        float2 a = lbuf[band * 2][rl];
        float2 b = lbuf[band * 2 + 1][rl];
        float mc = fmaxf(a.x, b.x);
        float sc = a.y * __expf(a.x - mc) + b.y * __expf(b.x - mc);
        P[(size_t)(m0 + band * 64 + rl) * NT + (n0 >> 7)] = make_float2(mc, sc);
    }
}

// ---------------- MFMA flash attention, KV-split-2 ----------------
__global__ __launch_bounds__(256) void attn3_kernel(const bf16* __restrict__ qkv,
                                                    float* __restrict__ po,
                                                    float2* __restrict__ pml) {
    __shared__ bf16 Vt[64 * 64];
    __shared__ bf16 Ps[4][16 * 64];
    const int bid = blockIdx.x;
    const int z = blockIdx.y;
    const int q0 = (15 - (bid & 15)) * 64;
    const int h  = (bid / (TT / 64)) % HH;
    const int b  = bid / ((TT / 64) * HH);
    const int tid = threadIdx.x, lane = tid & 63, wid = tid >> 6;
    const int fr = lane & 15, fq = lane >> 4;
    const size_t rs = 3 * DD;

    const int nt_all = q0 / 64 + 1;
    const int lo = z ? (nt_all + 1) / 2 : 0;
    const int hi = z ? nt_all : (nt_all + 1) / 2;

    po  += (size_t)z * MROWS * DD;
    pml += (size_t)z * NROWS;

    if (lo >= hi) {
        #pragma unroll
        for (int r = 0; r < 4; ++r) {
            int q = q0 + wid * 16 + fq * 4 + r;
            size_t pidx = ((size_t)(b * TT + q) * HH + h);
            #pragma unroll
            for (int n2 = 0; n2 < 4; ++n2)
                po[pidx * NHD + n2 * 16 + fr] = 0.f;
            if (fr == 0) pml[pidx] = make_float2(-1e30f, 0.f);
        }
        return;
    }

    bf16x8 qf[2];
    {
        const bf16* qb = qkv + (size_t)(b * TT + q0 + wid * 16 + fr) * rs + h * NHD;
        qf[0] = *(const bf16x8*)(qb + fq * 8);
        qf[1] = *(const bf16x8*)(qb + 32 + fq * 8);
    }
    float mrun[4] = {-1e30f, -1e30f, -1e30f, -1e30f};
    float lrun[4] = {0.f, 0.f, 0.f, 0.f};
    f32x4 o[4] = {};
    const int vrow = (tid & 31) * 2, kq = tid >> 5;

    for (int jt = lo; jt < hi; ++jt) {
        __syncthreads();
        {
            const u16x8* vb = (const u16x8*)(qkv + (size_t)(b * TT + jt * 64 + vrow) * rs + 2 * DD + h * NHD + kq * 8);
            u16x8 v0 = vb[0];
            u16x8 v1 = *(const u16x8*)((const bf16*)vb + rs);
            #pragma unroll
            for (int j = 0; j < 8; ++j) {
                int d = kq * 8 + j;
                int e = (d * 64 + vrow) ^ ((d & 7) << 3);
                *(unsigned int*)&Vt[e] = (unsigned int)v0[j] | ((unsigned int)v1[j] << 16);
            }
        }
        f32x4 s[4] = {};
        const bf16* kb = qkv + (size_t)(b * TT + jt * 64 + fr) * rs + DD + h * NHD;
        __builtin_amdgcn_s_setprio(1);
        #pragma unroll
        for (int n = 0; n < 4; ++n) {
            bf16x8 k0 = *(const bf16x8*)(kb + (size_t)(n * 16) * rs + fq * 8);
            bf16x8 k1 = *(const bf16x8*)(kb + (size_t)(n * 16) * rs + 32 + fq * 8);
            s[n] = __builtin_amdgcn_mfma_f32_16x16x32_bf16(qf[0], k0, s[n], 0, 0, 0);
            s[n] = __builtin_amdgcn_mfma_f32_16x16x32_bf16(qf[1], k1, s[n], 0, 0, 0);
        }
        __builtin_amdgcn_s_setprio(0);
        float mt[4] = {-1e30f, -1e30f, -1e30f, -1e30f};
        #pragma unroll
        for (int n = 0; n < 4; ++n) {
            int colg = jt * 64 + n * 16 + fr;
            #pragma unroll
            for (int r = 0; r < 4; ++r) {
                int rowg = q0 + wid * 16 + fq * 4 + r;
                float v = s[n][r] * 0.125f;
                if (colg > rowg) v = -1e30f;
                s[n][r] = v;
                mt[r] = fmaxf(mt[r], v);
            }
        }
        #pragma unroll
        for (int msk = 1; msk <= 8; msk <<= 1)
            #pragma unroll
            for (int r = 0; r < 4; ++r) mt[r] = fmaxf(mt[r], __shfl_xor(mt[r], msk));
        float sc[4], pt[4] = {0.f, 0.f, 0.f, 0.f};
        #pragma unroll
        for (int r = 0; r < 4; ++r) {
            float mn = fmaxf(mrun[r], mt[r]);
            sc[r] = __expf(mrun[r] - mn);
            mrun[r] = mn;
        }
        #pragma unroll
        for (int n = 0; n < 4; ++n)
            #pragma unroll
            for (int r = 0; r < 4; ++r) {
                float p = __expf(s[n][r] - mrun[r]);
                s[n][r] = p;
                pt[r] += p;
            }
        #pragma unroll
        for (int msk = 1; msk <= 8; msk <<= 1)
            #pragma unroll
            for (int r = 0; r < 4; ++r) pt[r] += __shfl_xor(pt[r], msk);
        #pragma unroll
        for (int r = 0; r < 4; ++r) lrun[r] = lrun[r] * sc[r] + pt[r];
        #pragma unroll
        for (int n2 = 0; n2 < 4; ++n2)
            #pragma unroll
            for (int r = 0; r < 4; ++r) o[n2][r] *= sc[r];
        #pragma unroll
        for (int n = 0; n < 4; ++n)
            #pragma unroll
            for (int r = 0; r < 4; ++r) {
                int row = fq * 4 + r;
                int e = (row * 64 + n * 16 + fr) ^ ((row & 7) << 3);
                Ps[wid][e] = __float2bfloat16(s[n][r]);
            }
        __syncthreads();
        __builtin_amdgcn_s_setprio(1);
        #pragma unroll
        for (int ks = 0; ks < 2; ++ks) {
            int pe = (fr * 64 + ks * 32 + fq * 8) ^ ((fr & 7) << 3);
            bf16x8 pa = *(const bf16x8*)&Ps[wid][pe];
            #pragma unroll
            for (int n2 = 0; n2 < 4; ++n2) {
                int d = n2 * 16 + fr;
                int ve = (d * 64 + ks * 32 + fq * 8) ^ ((d & 7) << 3);
                bf16x8 vv = *(const bf16x8*)&Vt[ve];
                o[n2] = __builtin_amdgcn_mfma_f32_16x16x32_bf16(pa, vv, o[n2], 0, 0, 0);
            }
        }
        __builtin_amdgcn_s_setprio(0);
    }
    #pragma unroll
    for (int r = 0; r < 4; ++r) {
        int q = q0 + wid * 16 + fq * 4 + r;
        size_t pidx = ((size_t)(b * TT + q) * HH + h);
        #pragma unroll
        for (int n2 = 0; n2 < 4; ++n2)
            po[pidx * NHD + n2 * 16 + fr] = o[n2][r];
        if (fr == 0) pml[pidx] = make_float2(mrun[r], lrun[r]);
    }
}

// ---------------- attention combine: merge 2 KV-split partials -> ab ----------
__global__ void attn_combine(const float* __restrict__ po, const float2* __restrict__ pml,
                             bf16* __restrict__ out) {
    const size_t ZO = (size_t)MROWS * DD;
    int tid = threadIdx.x;
    size_t pidx = (size_t)blockIdx.x * 4 + (tid >> 6);
    int d = tid & 63;
    float2 a = pml[pidx];
    float2 b = pml[NROWS + pidx];
    float mt = fmaxf(a.x, b.x);
    float e0 = __expf(a.x - mt), e1 = __expf(b.x - mt);
    float l = a.y * e0 + b.y * e1;
    float ov = po[pidx * NHD + d] * e0 + po[ZO + pidx * NHD + d] * e1;
    int h = (int)(pidx % HH);
    size_t bt = pidx / HH;
    out[bt * DD + h * NHD + d] = __float2bfloat16(ov / l);
}

// ---------------- loss finish ----------------
__global__ void zero_kernel(float* p) { if (threadIdx.x == 0) p[0] = 0.f; }

__global__ void loss_finish(const float2* __restrict__ P, const float* __restrict__ logits,
                            const int* __restrict__ targets, float* __restrict__ acc) {
    __shared__ float rm[256], rs[256];
    int m = blockIdx.x;
    int tid = threadIdx.x;
    float mx = -1e30f, sm = 0.f;
    for (int i = tid; i < NT; i += 256) {
        float2 p = P[(size_t)m * NT + i];
        float nm = fmaxf(mx, p.x);
        sm = sm * __expf(mx - nm) + p.y * __expf(p.x - nm);
        mx = nm;
    }
    rm[tid] = mx; rs[tid] = sm;
    __syncthreads();
    for (int s = 128; s > 0; s >>= 1) {
        if (tid < s) {
            float m2 = rm[tid + s], s2 = rs[tid + s];
            float nm = fmaxf(rm[tid], m2);
            rs[tid] = rs[tid] * __expf(rm[tid] - nm) + s2 * __expf(m2 - nm);
            rm[tid] = nm;
        }
        __syncthreads();
    }
    if (tid == 0) {
        float lse = logf(rs[0]) + rm[0];
        atomicAdd(acc, lse - logits[(size_t)m * VV + targets[m]]);
    }
}

__global__ void loss_final(const float* __restrict__ acc, float* __restrict__ out) {
    if (threadIdx.x == 0) out[0] = acc[0] * (1.0f / (float)MROWS);
}

// ---------------- launch ----------------
extern "C" void kernel_launch(void* const* d_in, const int* in_sizes, int n_in,
                              void* d_out, int out_size, void* d_ws, size_t ws_size,
                              hipStream_t stream) {
    const int*   idx     = (const int*)d_in[0];
    const int*   targets = (const int*)d_in[1];
    const float* wte     = (const float*)d_in[2];
    const float* wpe     = (const float*)d_in[3];
    const float* ln1_w   = (const float*)d_in[4];
    const float* ln1_b   = (const float*)d_in[5];
    const float* qkv_w   = (const float*)d_in[6];
    const float* qkv_b   = (const float*)d_in[7];
    const float* proj_w  = (const float*)d_in[8];
    const float* proj_b  = (const float*)d_in[9];
    const float* ln2_w   = (const float*)d_in[10];
    const float* ln2_b   = (const float*)d_in[11];
    const float* fc_w    = (const float*)d_in[12];
    const float* fc_b    = (const float*)d_in[13];
    const float* fc2_w   = (const float*)d_in[14];
    const float* fc2_b   = (const float*)d_in[15];
    const float* lnf_w   = (const float*)d_in[16];
    const float* lnf_b   = (const float*)d_in[17];

    float* logits = (float*)d_out;
    float* loss_out = logits + (size_t)MROWS * VV;

    const size_t LQ = (size_t)3 * DD * DD, LP = (size_t)DD * DD;
    const size_t LF = (size_t)4 * DD * DD, LF2 = (size_t)4 * DD * DD;
    const size_t LSTRIDE = LQ + LP + LF + LF2;

    float* x    = (float*)d_ws;
    float* lacc = x + (size_t)MROWS * DD;
    float* part = lacc + 16;                                  // [2][MROWS*DD]; splitK out + attn po + loss P
    float2* pml = (float2*)(part + (size_t)2 * MROWS * DD);   // [2][NROWS]
    bf16* qkvbuf = (bf16*)(pml + (size_t)2 * NROWS);
    bf16* hb   = qkvbuf + (size_t)MROWS * 3 * DD;
    bf16* ab   = hb + (size_t)MROWS * DD;
    bf16* gb   = ab + (size_t)MROWS * DD;
    bf16* wteb = gb + (size_t)MROWS * 4 * DD;
    bf16* wbase = wteb + (size_t)VPAD * DD;

    const size_t fixed_bytes = (size_t)((char*)wbase - (char*)d_ws);
    const bool hoist = ws_size >= fixed_bytes + sizeof(bf16) * LSTRIDE * LL;

    dim3 blk(256);
    cast_kernel<<<2048, blk, 0, stream>>>(wte, wteb, VV * DD / 4);
    padzero_kernel<<<((VPAD - VV) * DD + 255) / 256, blk, 0, stream>>>(
        wteb + (size_t)VV * DD, (VPAD - VV) * DD);
    embed_kernel<<<MROWS, blk, 0, stream>>>(idx, wte, wpe, x);

    if (hoist) {
        tcast_kernel<<<dim3(3 * DD / 32, DD / 32, LL), blk, 0, stream>>>(
            qkv_w, wbase, DD, 3 * DD, LQ, LSTRIDE);
        tcast_kernel<<<dim3(DD / 32, DD / 32, LL), blk, 0, stream>>>(
            proj_w, wbase + LQ, DD, DD, LP, LSTRIDE);
        tcast_kernel<<<dim3(4 * DD / 32, DD / 32, LL), blk, 0, stream>>>(
            fc_w, wbase + LQ + LP, DD, 4 * DD, LF, LSTRIDE);
        tcast_kernel<<<dim3(DD / 32, 4 * DD / 32, LL), blk, 0, stream>>>(
            fc2_w, wbase + LQ + LP + LF, 4 * DD, DD, LF2, LSTRIDE);
    }

    ln_kernel<<<MROWS, blk, 0, stream>>>(x, ln1_w, ln1_b, hb);

    for (int l = 0; l < LL; ++l) {
        bf16* wl = hoist ? wbase + (size_t)l * LSTRIDE : wbase;
        bf16* wQT = wl, *wPT = wl + LQ, *wFT = wl + LQ + LP, *wF2T = wl + LQ + LP + LF;
        if (!hoist) {
            tcast_kernel<<<dim3(3 * DD / 32, DD / 32, 1), blk, 0, stream>>>(qkv_w + (size_t)l * LQ, wQT, DD, 3 * DD, 0, 0);
            tcast_kernel<<<dim3(DD / 32, DD / 32, 1), blk, 0, stream>>>(proj_w + (size_t)l * LP, wPT, DD, DD, 0, 0);
            tcast_kernel<<<dim3(4 * DD / 32, DD / 32, 1), blk, 0, stream>>>(fc_w + (size_t)l * LF, wFT, DD, 4 * DD, 0, 0);
            tcast_kernel<<<dim3(DD / 32, 4 * DD / 32, 1), blk, 0, stream>>>(fc2_w + (size_t)l * LF2, wF2T, 4 * DD, DD, 0, 0);
        }

        mgemm<128, 64, true, false, false, true, false><<<dim3(MROWS / 128, 3 * DD / 64), blk, 0, stream>>>(
            hb, wQT, qkv_b + (size_t)l * 3 * DD, nullptr, nullptr, qkvbuf, MROWS, 3 * DD, DD);

        attn3_kernel<<<dim3(BB * HH * (TT / 64), 2), blk, 0, stream>>>(qkvbuf, part, pml);
        attn_combine<<<NROWS / 4, blk, 0, stream>>>(part, pml, ab);

        mgemm<64, 64, false, false, false, false, true><<<dim3(MROWS / 64, DD / 64, 2), blk, 0, stream>>>(
            ab, wPT, nullptr, nullptr, part, nullptr, MROWS, DD, DD);
        redln_kernel<<<MROWS, blk, 0, stream>>>(part, proj_b + (size_t)l * DD,
            ln2_w + (size_t)l * DD, ln2_b + (size_t)l * DD, x, hb);

        mgemm<128, 64, true, true, false, true, false><<<dim3(MROWS / 128, 4 * DD / 64), blk, 0, stream>>>(
            hb, wFT, fc_b + (size_t)l * 4 * DD, nullptr, nullptr, gb, MROWS, 4 * DD, DD);

        mgemm<64, 64, false, false, false, false, true><<<dim3(MROWS / 64, DD / 64, 2), blk, 0, stream>>>(
            gb, wF2T, nullptr, nullptr, part, nullptr, MROWS, DD, 4 * DD);
        const float* nw = (l + 1 < LL) ? ln1_w + (size_t)(l + 1) * DD : lnf_w;
        const float* nb = (l + 1 < LL) ? ln1_b + (size_t)(l + 1) * DD : lnf_b;
        redln_kernel<<<MROWS, blk, 0, stream>>>(part, fc2_b + (size_t)l * DD, nw, nb, x, hb);
    }

    mgemmL<<<dim3(MROWS / 256, VPAD / 128), dim3(512), 0, stream>>>(
        hb, wteb, logits, (float2*)part, VV, DD);

    zero_kernel<<<1, 64, 0, stream>>>(lacc);
    loss_finish<<<MROWS, blk, 0, stream>>>((const float2*)part, logits, targets, lacc);
    loss_final<<<1, 64, 0, stream>>>(lacc, loss_out);
}